// Round 3
// baseline (167.847 us; speedup 1.0000x reference)
//
#include <hip/hip_runtime.h>
#include <hip/hip_bf16.h>

#define B_    4
#define S_    2048
#define HID_  768
#define H_    12
#define DBLK_ 256
#define HD_   64
#define BH_   (B_ * H_)                 // 48
#define QSZ_  (B_ * H_ * S_ * HD_)      // 6291456 elements
#define WTSZ_ (3 * H_ * HD_ * DBLK_)    // 589824 elements

typedef _Float16 f16x4 __attribute__((ext_vector_type(4)));
typedef _Float16 f16x8 __attribute__((ext_vector_type(8)));
typedef float    f32x4 __attribute__((ext_vector_type(4)));
typedef float    f32x16 __attribute__((ext_vector_type(16)));

#if __has_builtin(__builtin_amdgcn_exp2f)
#define EXP2(x) __builtin_amdgcn_exp2f(x)
#else
#define EXP2(x) exp2f(x)
#endif

typedef const void __attribute__((address_space(1)))* gptr_t;
typedef       void __attribute__((address_space(3)))* sptr_t;

// ---------------------------------------------------------------------------
// Kernel 0: W fp32 -> f16 in exact MFMA B-fragment order (unchanged).
// ---------------------------------------------------------------------------
__global__ __launch_bounds__(256) void wconv(
    const float* __restrict__ Wq, const float* __restrict__ Wk,
    const float* __restrict__ Wv, _Float16* __restrict__ whf)
{
    const int idx  = blockIdx.x * 256 + threadIdx.x;
    const int j    = idx & 7;
    const int lane = (idx >> 3) & 63;
    const int et   = (idx >> 9) & 1;
    const int kk   = (idx >> 10) & 7;
    const int eh   = (idx >> 13) & 1;
    const int ph   = idx >> 14;          // p*12 + h
    const int h    = ph % H_;
    const int p    = ph / H_;
    const int e = eh * 32 + et * 16 + (lane & 15);
    const int k = kk * 32 + (lane >> 4) * 8 + j;
    const float* W = (p == 0) ? Wq : (p == 1) ? Wk : Wv;
    whf[idx] = (_Float16)W[((size_t)h * DBLK_ + k) * HD_ + e];
}

// ---------------------------------------------------------------------------
// Kernel 1: block-diagonal QKV projection (unchanged from R1/R2: K rows
// stored with bit2<->bit3 swap; chunk-XOR swizzles on K/V tiles).
// ---------------------------------------------------------------------------
__global__ __launch_bounds__(256, 3) void qkv_proj(
    const float* __restrict__ x, const _Float16* __restrict__ whf,
    const float* __restrict__ bq, const float* __restrict__ bk,
    const float* __restrict__ bv,
    _Float16* __restrict__ qo, _Float16* __restrict__ khf,
    _Float16* __restrict__ vtf)
{
    const int i   = blockIdx.x;          // g*128 + sc
    const int g   = i >> 7;              // 0..5
    const int sc  = i & 127;
    const int m   = g >> 1;
    const int s0g = sc * 64;

    const int tid  = threadIdx.x;
    const int lane = tid & 63;
    const int w    = tid >> 6;
    const int ln   = lane & 15;
    const int qd   = lane >> 4;
    const int h    = 2 * g + (w >> 1);
    const int eh   = w & 1;

    __shared__ _Float16 xs[64 * 256];    // 32 KB, reused by the epilogue

    {   // stage X: 64 rows x 256 cols, fp32 -> f16, 16B-granule XOR swizzle
        const int rr   = tid >> 6;
        const int c4   = tid & 63;
        const int g16  = c4 >> 1;
        const int half = c4 & 1;
        #pragma unroll
        for (int pass = 0; pass < 16; pass++) {
            const int r = pass * 4 + rr;
            const float4 v = *(const float4*)(
                x + (size_t)(s0g + r) * HID_ + m * DBLK_ + c4 * 4);
            f16x4 hv;
            hv[0] = (_Float16)v.x; hv[1] = (_Float16)v.y;
            hv[2] = (_Float16)v.z; hv[3] = (_Float16)v.w;
            *(f16x4*)(xs + r * 256 + ((g16 ^ (r & 7)) * 8) + half * 4) = hv;
        }
    }
    __syncthreads();

    f32x4 acc[3][2][4];                  // [p][et][strip]
    #pragma unroll
    for (int p = 0; p < 3; p++)
        #pragma unroll
        for (int et = 0; et < 2; et++)
            #pragma unroll
            for (int st = 0; st < 4; st++)
                acc[p][et][st] = (f32x4){0.f, 0.f, 0.f, 0.f};

    const _Float16* wb = whf + (size_t)((h * 2 + eh) * 16) * 512 + lane * 8;

    for (int kk = 0; kk < 8; kk++) {
        f16x8 a[4];
        #pragma unroll
        for (int st = 0; st < 4; st++)
            a[st] = *(const f16x8*)(
                xs + (st * 16 + ln) * 256 + (((kk * 4 + qd) ^ (ln & 7)) * 8));
        #pragma unroll
        for (int p = 0; p < 3; p++)
            #pragma unroll
            for (int et = 0; et < 2; et++) {
                const f16x8 bb = *(const f16x8*)(
                    wb + (size_t)p * 196608 + (kk * 2 + et) * 512);
                #pragma unroll
                for (int st = 0; st < 4; st++)
                    acc[p][et][st] = __builtin_amdgcn_mfma_f32_16x16x32_f16(
                        a[st], bb, acc[p][et][st], 0, 0, 0);
            }
    }

    const float QS = 0.18033688011112042f;   // 0.125 * log2(e)
    const int b    = s0g >> 11;
    const int s0   = s0g & 2047;
    const int bhh  = b * H_ + h;
    const int tile = s0 >> 6;
    const int ht   = w >> 1;

    __syncthreads();                      // xs MFMA reads done; reuse as Q/K tiles
    // xs layout: Q tiles [ht][64 rows][8 chunks], K tiles at +8192 elems.
    // Both stored with chunk pos = c ^ (row&7). K rows bit2<->bit3 swapped.
    {
        _Float16* qtile = xs + ht * 4096;
        _Float16* ktile = xs + 8192 + ht * 4096;
        const size_t tbv = (size_t)(bhh * 32 + tile) * 4096;
        #pragma unroll
        for (int et = 0; et < 2; et++) {
            const int d  = eh * 32 + et * 16 + ln;
            const int dc = d >> 3, d7 = d & 7;
            const float biasq = bq[h * HD_ + d];
            const float biask = bk[h * HD_ + d];
            const float biasv = bv[h * HD_ + d];
            #pragma unroll
            for (int st = 0; st < 4; st++) {
                // V: direct global store, f16x4, swizzled V^T tile [d][kv]
                f16x4 vv;
                #pragma unroll
                for (int r = 0; r < 4; r++) vv[r] = (_Float16)(acc[2][et][st][r] + biasv);
                const int vc = st * 2 + (qd >> 1);
                *(f16x4*)(vtf + tbv + d * 64 + ((vc ^ d7) * 8) + (qd & 1) * 4) = vv;
                // Q/K into LDS (transpose staging)
                #pragma unroll
                for (int r = 0; r < 4; r++) {
                    const int sl  = st * 16 + qd * 4 + r;
                    // token sl = st*16 + qd*4 + r; row = swap(bit2,bit3)(sl)
                    const int rho = st * 16 + (qd & 1) * 8 + (qd >> 1) * 4 + r;
                    qtile[sl  * 64 + ((dc ^ (sl  & 7)) * 8) + d7] =
                        (_Float16)((acc[0][et][st][r] + biasq) * QS);
                    ktile[rho * 64 + ((dc ^ (rho & 7)) * 8) + d7] =
                        (_Float16)(acc[1][et][st][r] + biask);
                }
            }
        }
    }
    __syncthreads();
    // copy-out: 4 b128 Q + 4 b128 K per thread, fully coalesced global stores
    #pragma unroll
    for (int it = 0; it < 4; it++) {
        const int idx  = it * 256 + tid;      // 0..1023
        const int ht2  = idx >> 9;
        const int rest = idx & 511;
        const int row  = rest >> 3;
        const int c    = rest & 7;
        const int bhh2 = b * H_ + 2 * g + ht2;
        // Q: unswizzle (read pos c^(row&7), write chunk c), natural row order
        const f16x8 qv = *(const f16x8*)(xs + ht2 * 4096 + row * 64 + ((c ^ (row & 7)) * 8));
        *(f16x8*)(qo + ((size_t)bhh2 * S_ + s0 + row) * HD_ + c * 8) = qv;
        // K: swizzle is part of the global tile layout -> linear copy
        const f16x8 kv8 = *(const f16x8*)(xs + 8192 + ht2 * 4096 + row * 64 + c * 8);
        *(f16x8*)(khf + (size_t)(bhh2 * 32 + tile) * 4096 + row * 64 + c * 8) = kv8;
    }
}

// ---------------------------------------------------------------------------
// Kernel 2: flash attention. R3: 2x2 wave split to halve LDS read traffic.
// Wave (wk,wq) = (w>>1, w&1) owns kv rows wk*32..+32 and q cols wq*64..+64.
// R2 analysis: LDS unit is the CU bottleneck (12 waves x 16 b128 x 12cy =
// 2304cy/iter/CU vs 1776cy MFMA) because all 4 waves read IDENTICAL frags.
// Split: 8 reads/wave (kf 4 + vf 4), same 16 MFMA/wave (2 qt2 x (4 QK + 4 PV)).
// k-slot algebra unchanged: sigma = bit2<->bit3 swap acts within 32-blocks,
// so C-reg r=ks*8+j at group g still holds token 16ks+8g+j.
// Cost: one-time cross-wk O/l reduction through LDS at the end.
// ---------------------------------------------------------------------------
__global__ __launch_bounds__(256, 3) void attn(
    const _Float16* __restrict__ qh, const _Float16* __restrict__ khf,
    const _Float16* __restrict__ vtf, float* __restrict__ out)
{
    const int i    = blockIdx.x;          // 0..767
    const int slot = i >> 3;
    const int bh   = (i & 7) * 6 + (slot % 6);   // XCD-banded bh
    const int qt   = slot / 6;            // 0..15
    const int h = bh % H_, b = bh / H_;
    const int q0 = qt * 128;

    const int tid  = threadIdx.x;
    const int lane = tid & 63;
    const int w    = tid >> 6;
    const int wk   = w >> 1;              // kv-half owner
    const int wq   = w & 1;               // q-half owner
    const int l5   = lane & 31;
    const int g    = lane >> 5;
    const int x7   = l5 & 7;              // chunk-XOR key

    __shared__ __align__(16) char lds[2][16384];   // [buf][ K 8KB | V 8KB ]

    // Q B-frags for 64 q (2 tiles of 32), pre-scaled by 0.125*log2e
    f16x8 qf[2][4];
    #pragma unroll
    for (int qt2 = 0; qt2 < 2; qt2++) {
        const _Float16* qb = qh +
            ((size_t)bh * S_ + q0 + wq * 64 + qt2 * 32 + l5) * HD_;
        #pragma unroll
        for (int kk = 0; kk < 4; kk++)
            qf[qt2][kk] = *(const f16x8*)(qb + kk * 16 + g * 8);
    }

    f32x16 o[2][2];                       // [qt2][dt]
    #pragma unroll
    for (int qt2 = 0; qt2 < 2; qt2++)
        #pragma unroll
        for (int dt = 0; dt < 2; dt++)
            #pragma unroll
            for (int r = 0; r < 16; r++) o[qt2][dt][r] = 0.f;
    float lp[2] = {0.f, 0.f};

    const char* kbase = (const char*)(khf + (size_t)bh * 32 * 4096);
    const char* vbase = (const char*)(vtf + (size_t)bh * 32 * 4096);
    const int   seg   = w * 1024 + lane * 16;
    const int   wseg  = w * 1024;

    auto dma = [&](int it, int buf) {
        const char* ks = kbase + (size_t)it * 8192;
        const char* vs = vbase + (size_t)it * 8192;
        char* lk = &lds[buf][0];
        char* lv = &lds[buf][8192];
        #pragma unroll
        for (int q = 0; q < 2; q++) {
            __builtin_amdgcn_global_load_lds(
                (gptr_t)(ks + q * 4096 + seg), (sptr_t)(lk + q * 4096 + wseg), 16, 0, 0);
            __builtin_amdgcn_global_load_lds(
                (gptr_t)(vs + q * 4096 + seg), (sptr_t)(lv + q * 4096 + wseg), 16, 0, 0);
        }
    };

    dma(0, 0);

    for (int it = 0; it < 32; it++) {
        const int buf = it & 1;
        __syncthreads();
        if (it + 1 < 32) dma(it + 1, buf ^ 1);

        const char* lk = &lds[buf][0];
        const char* lv = &lds[buf][8192];

        // This wave's kv-half only: 4 K-frag + 4 V-frag b128 reads.
        f16x8 kf[4];
        #pragma unroll
        for (int kk = 0; kk < 4; kk++)
            kf[kk] = *(const f16x8*)(
                lk + (wk * 32 + l5) * 128 + (((kk * 2 + g) ^ x7) * 16));
        f16x8 vf[2][2];
        #pragma unroll
        for (int dt = 0; dt < 2; dt++)
            #pragma unroll
            for (int ks = 0; ks < 2; ks++)
                vf[dt][ks] = *(const f16x8*)(
                    lv + (dt * 32 + l5) * 128 + (((wk * 4 + ks * 2 + g) ^ x7) * 16));

        #pragma unroll
        for (int qt2 = 0; qt2 < 2; qt2++) {
            // QK^T: S^T[kv32][q32], rows = this wave's kv-half
            f32x16 c;
            #pragma unroll
            for (int r = 0; r < 16; r++) c[r] = 0.f;
            #pragma unroll
            for (int kk = 0; kk < 4; kk++)
                c = __builtin_amdgcn_mfma_f32_32x32x16_f16(
                    kf[kk], qf[qt2][kk], c, 0, 0, 0);

            // exp2 + pack into PV A-frags; f32 row-sum for l
            f16x8 a[2];
            #pragma unroll
            for (int ks = 0; ks < 2; ks++) {
                float e[8];
                #pragma unroll
                for (int j = 0; j < 8; j++) {
                    e[j] = EXP2(c[ks * 8 + j]);
                    a[ks][j] = (_Float16)e[j];
                }
                lp[qt2] += ((e[0] + e[1]) + (e[2] + e[3]))
                         + ((e[4] + e[5]) + (e[6] + e[7]));
            }

            // PV: o[q32][d64] partial over this wave's 32 kv
            #pragma unroll
            for (int dt = 0; dt < 2; dt++)
                #pragma unroll
                for (int ks = 0; ks < 2; ks++)
                    o[qt2][dt] = __builtin_amdgcn_mfma_f32_32x32x16_f16(
                        a[ks], vf[dt][ks], o[qt2][dt], 0, 0, 0);
        }
    }

    // ---- epilogue: wk-pair reduction of l and O through LDS (one-time) ----
    float lf[2];
    #pragma unroll
    for (int qt2 = 0; qt2 < 2; qt2++)
        lf[qt2] = lp[qt2] + __shfl_xor(lp[qt2], 32, 64);

    __syncthreads();                      // all tile reads done; lds is scratch
    float* lbuf = (float*)(void*)&lds[0][0];        // [wq][qt2][32] = 512 B
    if (wk == 1 && lane < 32) {
        lbuf[(wq * 2 + 0) * 32 + l5] = lf[0];
        lbuf[(wq * 2 + 1) * 32 + l5] = lf[1];
    }
    __syncthreads();
    if (wk == 0 && lane < 32) {
        const float t0 = lf[0] + lbuf[(wq * 2 + 0) * 32 + l5];
        const float t1 = lf[1] + lbuf[(wq * 2 + 1) * 32 + l5];
        lbuf[(wq * 2 + 0) * 32 + l5] = 1.f / t0;
        lbuf[(wq * 2 + 1) * 32 + l5] = 1.f / t1;
    }

    char* obuf = &lds[0][1024];           // 16 KB scratch, reused per qt2 phase
    #pragma unroll
    for (int qt2 = 0; qt2 < 2; qt2++) {
        __syncthreads();                  // inv ready / prev phase reads done
        if (wk == 1) {
            #pragma unroll
            for (int dt = 0; dt < 2; dt++)
                #pragma unroll
                for (int p = 0; p < 4; p++) {
                    f32x4 v4;
                    v4[0] = o[qt2][dt][4 * p + 0];
                    v4[1] = o[qt2][dt][4 * p + 1];
                    v4[2] = o[qt2][dt][4 * p + 2];
                    v4[3] = o[qt2][dt][4 * p + 3];
                    *(f32x4*)(obuf + (wq * 2 + dt) * 4096 + p * 1024 + lane * 16) = v4;
                }
        }
        __syncthreads();
        if (wk == 0) {
            #pragma unroll
            for (int dt = 0; dt < 2; dt++) {
                #pragma unroll
                for (int p = 0; p < 4; p++) {
                    const f32x4 v4 = *(const f32x4*)(
                        obuf + (wq * 2 + dt) * 4096 + p * 1024 + lane * 16);
                    o[qt2][dt][4 * p + 0] += v4[0];
                    o[qt2][dt][4 * p + 1] += v4[1];
                    o[qt2][dt][4 * p + 2] += v4[2];
                    o[qt2][dt][4 * p + 3] += v4[3];
                }
                #pragma unroll
                for (int r = 0; r < 16; r++) {
                    const int qrow = (r & 3) + 8 * (r >> 2) + 4 * g;
                    const float li = lbuf[(wq * 2 + qt2) * 32 + qrow];
                    out[((size_t)b * S_ + q0 + wq * 64 + qt2 * 32 + qrow) * HID_
                        + (size_t)h * HD_ + dt * 32 + l5] = o[qt2][dt][r] * li;
                }
            }
        }
    }
}

// ---------------------------------------------------------------------------
extern "C" void kernel_launch(void* const* d_in, const int* in_sizes, int n_in,
                              void* d_out, int out_size, void* d_ws, size_t ws_size,
                              hipStream_t stream) {
    const float* x  = (const float*)d_in[0];
    const float* Wq = (const float*)d_in[1];
    const float* bq = (const float*)d_in[2];
    const float* Wk = (const float*)d_in[3];
    const float* bk = (const float*)d_in[4];
    const float* Wv = (const float*)d_in[5];
    const float* bv = (const float*)d_in[6];
    float* out = (float*)d_out;

    _Float16* q  = (_Float16*)d_ws;
    _Float16* k  = q + QSZ_;
    _Float16* vt = k + QSZ_;
    const size_t need = ((size_t)3 * QSZ_ + WTSZ_) * sizeof(_Float16);
    _Float16* wh = (ws_size >= need) ? (vt + QSZ_)
                                     : (_Float16*)d_out;  // consumed before attn writes out

    wconv<<<WTSZ_ / 256, 256, 0, stream>>>(Wq, Wk, Wv, wh);
    qkv_proj<<<768, 256, 0, stream>>>(x, wh, bq, bk, bv, q, k, vt);
    attn<<<768, 256, 0, stream>>>(q, k, vt, out);
}